// Round 2
// baseline (702.566 us; speedup 1.0000x reference)
//
#include <hip/hip_runtime.h>
#include <math.h>

#define DD   120
#define KPAD 128
#define KP   136          // LDS row stride in bf16 elements (272 B)
#define MT   64           // points per tile
#define NTHR 512          // 8 waves; wave h owns head h (cols 15h..15h+14)
#define HASH_MASK 1048575LL
#define MODT 201
#define MAXGRID 768       // 3 blocks/CU if LDS allows (3*53KB < 160KB)

typedef short  short8  __attribute__((ext_vector_type(8)));
typedef float  floatx4 __attribute__((ext_vector_type(4)));

__device__ __forceinline__ unsigned short f2b(float f) {
    __bf16 h = (__bf16)f;                       // RNE hardware cvt
    return __builtin_bit_cast(unsigned short, h);
}
__device__ __forceinline__ float b2f(unsigned short u) {
    unsigned int x = ((unsigned int)u) << 16;   // exact widening
    return __builtin_bit_cast(float, x);
}
__device__ __forceinline__ float rsum16(float v) {
    v += __shfl_xor(v, 1, 16);
    v += __shfl_xor(v, 2, 16);
    v += __shfl_xor(v, 4, 16);
    v += __shfl_xor(v, 8, 16);
    return v;
}
__device__ __forceinline__ uint2 pack4(float4 v) {
    unsigned int lo = (unsigned int)f2b(v.x) | ((unsigned int)f2b(v.y) << 16);
    unsigned int hi = (unsigned int)f2b(v.z) | ((unsigned int)f2b(v.w) << 16);
    return make_uint2(lo, hi);
}

// ---------------------------------------------------------------------------
// Pre-pass 1: weights fp32 [K=120][N=120] -> bf16 W^T padded [N=128][K=128].
// ---------------------------------------------------------------------------
__global__ __launch_bounds__(256)
void prep_weights(const float* __restrict__ td_w, const float* __restrict__ sd_w,
                  unsigned short* __restrict__ wt)
{
    int idx = blockIdx.x * 256 + threadIdx.x;   // 8*128*128 = 131072 total
    int mat = idx >> 14;
    int k   = (idx >> 7) & 127;
    int n   = idx & 127;
    const float* src = (mat < 4) ? (td_w + mat * DD * DD) : (sd_w + (mat - 4) * DD * DD);
    float v = (n < DD && k < DD) ? src[k * DD + n] : 0.f;
    wt[(mat << 14) + (n << 7) + k] = f2b(v);
}

// ---------------------------------------------------------------------------
// Pre-pass 2: k1t[t] = te[t]@W1+b1, v1t[t] = te[t]@W2+b2 for 201 time rows.
// ---------------------------------------------------------------------------
__global__ __launch_bounds__(128)
void prep_te(const float* __restrict__ temb, const float* __restrict__ td_w,
             const float* __restrict__ td_b,
             unsigned short* __restrict__ k1t, unsigned short* __restrict__ v1t)
{
    int t = blockIdx.x;      // 0..200
    int n = threadIdx.x;     // 0..127
    float a1 = 0.f, a2 = 0.f;
    if (n < DD) {
        a1 = td_b[DD + n];
        a2 = td_b[2 * DD + n];
        const float* te = temb + t * DD;
        const float* w1 = td_w + 1 * DD * DD;
        const float* w2 = td_w + 2 * DD * DD;
        for (int k = 0; k < DD; k++) {
            float x = te[k];
            a1 = fmaf(x, w1[k * DD + n], a1);
            a2 = fmaf(x, w2[k * DD + n], a2);
        }
    }
    k1t[t * KPAD + n] = f2b(a1);
    v1t[t * KPAD + n] = f2b(a2);
}

// ---------------------------------------------------------------------------
// GEMM pass: OUT[64 x 128] = IN[64 x 128] @ W + bias, this wave's N-tile.
// ---------------------------------------------------------------------------
__device__ __forceinline__ void gemm_tile(const unsigned short* IN,
                                          const unsigned short* __restrict__ WT,
                                          const float* __restrict__ bias,
                                          unsigned short* OUT,
                                          int lm, int lq, int n0)
{
    const int n = n0 + lm;
    short8 bfr[4];
#pragma unroll
    for (int ks = 0; ks < 4; ks++)
        bfr[ks] = *(const short8*)(WT + n * KPAD + ks * 32 + lq * 8);
    float bv = (n < DD) ? bias[n] : 0.f;
#pragma unroll
    for (int mt = 0; mt < 4; mt++) {
        floatx4 acc = {0.f, 0.f, 0.f, 0.f};
#pragma unroll
        for (int ks = 0; ks < 4; ks++) {
            short8 a = *(const short8*)(IN + (mt * 16 + lm) * KP + ks * 32 + lq * 8);
            acc = __builtin_amdgcn_mfma_f32_16x16x32_bf16(a, bfr[ks], acc, 0, 0, 0);
        }
#pragma unroll
        for (int r = 0; r < 4; r++)
            OUT[(mt * 16 + lq * 4 + r) * KP + n] = f2b(acc[r] + bv);
    }
}

// Final pass: fp32 store straight to global, masked by valid.
__device__ __forceinline__ void gemm_out(const unsigned short* IN,
                                         const unsigned short* __restrict__ WT,
                                         const float* __restrict__ bias,
                                         float* __restrict__ out,
                                         const int* s_valid, int pbase, int Mpts,
                                         int lm, int lq, int n0)
{
    const int n = n0 + lm;
    short8 bfr[4];
#pragma unroll
    for (int ks = 0; ks < 4; ks++)
        bfr[ks] = *(const short8*)(WT + n * KPAD + ks * 32 + lq * 8);
    float bv = (n < DD) ? bias[n] : 0.f;
#pragma unroll
    for (int mt = 0; mt < 4; mt++) {
        floatx4 acc = {0.f, 0.f, 0.f, 0.f};
#pragma unroll
        for (int ks = 0; ks < 4; ks++) {
            short8 a = *(const short8*)(IN + (mt * 16 + lm) * KP + ks * 32 + lq * 8);
            acc = __builtin_amdgcn_mfma_f32_16x16x32_bf16(a, bfr[ks], acc, 0, 0, 0);
        }
        if (n < DD) {
#pragma unroll
            for (int r = 0; r < 4; r++) {
                int row = mt * 16 + lq * 4 + r;
                int gp = pbase + row;
                if (gp < Mpts)
                    out[(size_t)gp * DD + n] = s_valid[row] ? (acc[r] + bv) : 0.f;
            }
        }
    }
}

__global__ __launch_bounds__(NTHR, 4)
void voxel_mfma_kernel(const float* __restrict__ pts,
                       const int* __restrict__ times,
                       const int* __restrict__ vox_buf,
                       const float* __restrict__ stat_f,
                       const float* __restrict__ dyn_f,
                       const float* __restrict__ td_b,
                       const float* __restrict__ sd_b,
                       const unsigned short* __restrict__ wt,
                       const unsigned short* __restrict__ k1t,
                       const unsigned short* __restrict__ v1t,
                       float* __restrict__ out,
                       int Mpts)
{
    __shared__ __align__(16) unsigned short sA[MT * KP];
    __shared__ __align__(16) unsigned short sC[MT * KP];
    __shared__ __align__(16) unsigned short sO[MT * KP];
    __shared__ __align__(16) int s_vi[2][MT];
    __shared__ __align__(16) int s_valid[2][MT];
    __shared__ __align__(16) int s_ti[2][MT];

    const int tid  = threadIdx.x;
    const int lane = tid & 63;
    const int lm   = lane & 15;
    const int lq   = lane >> 4;
    const int wv   = tid >> 6;          // wave id = head id
    const int n0h  = wv * 15;           // head-aligned col base (reg QKV passes)
    const int n0t  = wv * 16;           // 16-col tiles (cond / out gemm)
    const int nn   = n0h + lm;          // this lane's col in reg passes (<=120)
    const float scale = 0.2581988897471611f;   // 1/sqrt(15)
    const float msk = (lm < 15) ? 1.f : 0.f;   // col 15h+15 belongs to head h+1
    const int ntiles = (Mpts + MT - 1) / MT;

    if ((int)blockIdx.x >= ntiles) return;

    // biases (invariant across tiles; nn max = 120, arrays have 4*120 entries)
    const float f1bq = td_b[nn];
    const float f1bk = td_b[120 + nn];
    const float f1bv = td_b[240 + nn];
    const float f2bq = sd_b[nn];
    const float f2bk = sd_b[120 + nn];
    const float f2bv = sd_b[240 + nn];

    // ---- prologue: zero K-pads of sA/sO; meta for first tile ----------------
    if (tid < 256) {
        int b = tid >> 7, p = (tid >> 1) & 63, q = tid & 1;
        unsigned short* B = b ? sO : sA;
        *(uint2*)(B + p * KP + 120 + q * 4) = make_uint2(0u, 0u);
    }
    if (tid < MT) {
        int p = blockIdx.x * MT + tid;
        int vi = 0, valid = 0, ti = 0;
        if (p < Mpts) {
            float x = pts[3 * p + 0];
            float y = pts[3 * p + 1];
            float z = pts[3 * p + 2];
            long long gx = (long long)floorf(x / 0.1f);
            long long gy = (long long)floorf(y / 0.1f);
            long long gz = (long long)floorf(z / 0.1f);
            long long hh = (gx * 73856093LL + gy * 19349669LL + gz * 83492791LL) & HASH_MASK;
            int v = vox_buf[(int)hh];
            valid = (v >= 0) ? 1 : 0;
            vi = (v >= 0) ? v : 0;
            ti = times[p] % MODT;
        }
        s_vi[0][tid] = vi; s_valid[0][tid] = valid; s_ti[0][tid] = ti;
    }
    __syncthreads();
    // prologue df gather for first tile
    for (int i = tid; i < MT * 30; i += NTHR) {
        int p = i / 30, f = i % 30;
        float4 v = *(const float4*)(dyn_f + (size_t)s_vi[0][p] * DD + f * 4);
        *(uint2*)(sA + p * KP + f * 4) = pack4(v);
    }
    __syncthreads();

    int cur = 0;
    for (int tile = blockIdx.x; tile < ntiles; tile += gridDim.x) {
        const int pbase   = tile * MT;
        const int nxtile  = tile + gridDim.x;
        const bool hasnext = (nxtile < ntiles);
        const int nxt = cur ^ 1;

        // ================= phase F1: fusion 1 (reads sA, s_ti[cur] -> sO) ====
        // + prefetch: issue pts/times loads for tile i+1 (wave 0)
        float npx = 0.f, npy = 0.f, npz = 0.f; int ntim = 0;
        if (hasnext && tid < MT) {
            int p = nxtile * MT + tid;
            if (p < Mpts) {
                npx = pts[3 * p + 0];
                npy = pts[3 * p + 1];
                npz = pts[3 * p + 2];
                ntim = times[p];
            }
        }
        {
            const unsigned short* w0 = wt + 0 * 16384;
            const unsigned short* w1 = wt + 1 * 16384;
            const unsigned short* w2 = wt + 2 * 16384;
            short8 bq[4], bk[4], bvv[4];
#pragma unroll
            for (int ks = 0; ks < 4; ks++) {
                bq[ks]  = *(const short8*)(w0 + nn * KPAD + ks * 32 + lq * 8);
                bk[ks]  = *(const short8*)(w1 + nn * KPAD + ks * 32 + lq * 8);
                bvv[ks] = *(const short8*)(w2 + nn * KPAD + ks * 32 + lq * 8);
            }
#pragma unroll
            for (int mt = 0; mt < 4; mt++) {
                short8 a[4];
#pragma unroll
                for (int ks = 0; ks < 4; ks++)
                    a[ks] = *(const short8*)(sA + (mt * 16 + lm) * KP + ks * 32 + lq * 8);
                int4 tiv = *(const int4*)(&s_ti[cur][mt * 16 + lq * 4]);
                int tt[4] = {tiv.x, tiv.y, tiv.z, tiv.w};
                float k1v[4], v1v[4];
#pragma unroll
                for (int r = 0; r < 4; r++) {
                    k1v[r] = b2f(k1t[tt[r] * KPAD + nn]);   // bias folded in
                    v1v[r] = b2f(v1t[tt[r] * KPAD + nn]);
                }
                floatx4 q = {0.f,0.f,0.f,0.f}, k0 = {0.f,0.f,0.f,0.f}, v0 = {0.f,0.f,0.f,0.f};
#pragma unroll
                for (int ks = 0; ks < 4; ks++) {
                    q  = __builtin_amdgcn_mfma_f32_16x16x32_bf16(a[ks], bq[ks],  q,  0, 0, 0);
                    k0 = __builtin_amdgcn_mfma_f32_16x16x32_bf16(a[ks], bk[ks],  k0, 0, 0, 0);
                    v0 = __builtin_amdgcn_mfma_f32_16x16x32_bf16(a[ks], bvv[ks], v0, 0, 0, 0);
                }
#pragma unroll
                for (int r = 0; r < 4; r++) {
                    float qf = (q[r] + f1bq) * msk;
                    float c0 = rsum16(qf * (k0[r] + f1bk));
                    float c1 = rsum16(qf * k1v[r]);
                    float p0 = 1.f / (1.f + expf((c1 - c0) * scale));  // softmax[0]
                    float o  = p0 * (v0[r] + f1bv) + (1.f - p0) * v1v[r];
                    if (lm < 15)
                        sO[(mt * 16 + lq * 4 + r) * KP + nn] = f2b(o);
                }
            }
        }
        __syncthreads();

        // ======== phase COND: cond gemm (sO->sC) ∥ sf gather -> sA ===========
        // + prefetch: hash(i+1) and issue vox_buf load (wave 0)
        int nv = -1;
        if (hasnext && tid < MT) {
            int p = nxtile * MT + tid;
            if (p < Mpts) {
                long long gx = (long long)floorf(npx / 0.1f);
                long long gy = (long long)floorf(npy / 0.1f);
                long long gz = (long long)floorf(npz / 0.1f);
                long long hh = (gx * 73856093LL + gy * 19349669LL + gz * 83492791LL) & HASH_MASK;
                nv = vox_buf[(int)hh];
            }
        }
        {
            float4 g0, g1, g2, g3 = {0.f,0.f,0.f,0.f};
            int a0, a1, a2, a3 = -1;
            {
                int i = tid, p = i / 30, f = i % 30;
                g0 = *(const float4*)(stat_f + (size_t)s_vi[cur][p] * DD + f * 4);
                a0 = p * KP + f * 4;
                i += NTHR; p = i / 30; f = i % 30;
                g1 = *(const float4*)(stat_f + (size_t)s_vi[cur][p] * DD + f * 4);
                a1 = p * KP + f * 4;
                i += NTHR; p = i / 30; f = i % 30;
                g2 = *(const float4*)(stat_f + (size_t)s_vi[cur][p] * DD + f * 4);
                a2 = p * KP + f * 4;
                i += NTHR;
                if (i < MT * 30) {
                    p = i / 30; f = i % 30;
                    g3 = *(const float4*)(stat_f + (size_t)s_vi[cur][p] * DD + f * 4);
                    a3 = p * KP + f * 4;
                }
            }
            gemm_tile(sO, wt + 3 * 16384, td_b + 360, sC, lm, lq, n0t);
            *(uint2*)(sA + a0) = pack4(g0);
            *(uint2*)(sA + a1) = pack4(g1);
            *(uint2*)(sA + a2) = pack4(g2);
            if (a3 >= 0) *(uint2*)(sA + a3) = pack4(g3);
        }
        __syncthreads();

        // ================= phase F2: fusion 2 (reads sA,sC -> sO) ============
        // + prefetch: store meta(i+1) into buffer nxt (wave 0)
        if (hasnext && tid < MT) {
            s_vi[nxt][tid]    = (nv >= 0) ? nv : 0;
            s_valid[nxt][tid] = (nv >= 0) ? 1 : 0;
            s_ti[nxt][tid]    = ntim % MODT;
        }
        {
            const unsigned short* u0 = wt + 4 * 16384;
            const unsigned short* u1 = wt + 5 * 16384;
            const unsigned short* u2 = wt + 6 * 16384;
            short8 c1f[4], c2f[4];
#pragma unroll
            for (int ks = 0; ks < 4; ks++) {
                c1f[ks] = *(const short8*)(u1 + nn * KPAD + ks * 32 + lq * 8);
                c2f[ks] = *(const short8*)(u2 + nn * KPAD + ks * 32 + lq * 8);
            }
#pragma unroll
            for (int mt = 0; mt < 4; mt++) {
                short8 a[4], c[4];
#pragma unroll
                for (int ks = 0; ks < 4; ks++) {
                    a[ks] = *(const short8*)(sA + (mt * 16 + lm) * KP + ks * 32 + lq * 8);
                    c[ks] = *(const short8*)(sC + (mt * 16 + lm) * KP + ks * 32 + lq * 8);
                }
                floatx4 q = {0.f,0.f,0.f,0.f}, k20 = {0.f,0.f,0.f,0.f}, k21 = {0.f,0.f,0.f,0.f};
#pragma unroll
                for (int ks = 0; ks < 4; ks++) {
                    short8 b0 = *(const short8*)(u0 + nn * KPAD + ks * 32 + lq * 8);
                    q   = __builtin_amdgcn_mfma_f32_16x16x32_bf16(a[ks], b0,      q,   0, 0, 0);
                    k20 = __builtin_amdgcn_mfma_f32_16x16x32_bf16(a[ks], c1f[ks], k20, 0, 0, 0);
                    k21 = __builtin_amdgcn_mfma_f32_16x16x32_bf16(c[ks], c1f[ks], k21, 0, 0, 0);
                }
                float p0a[4];
#pragma unroll
                for (int r = 0; r < 4; r++) {
                    float qf = (q[r] + f2bq) * msk;
                    float c0 = rsum16(qf * (k20[r] + f2bk));
                    float c1 = rsum16(qf * (k21[r] + f2bk));
                    p0a[r] = 1.f / (1.f + expf((c1 - c0) * scale));
                }
                floatx4 v20 = {0.f,0.f,0.f,0.f}, v21 = {0.f,0.f,0.f,0.f};
#pragma unroll
                for (int ks = 0; ks < 4; ks++) {
                    v20 = __builtin_amdgcn_mfma_f32_16x16x32_bf16(a[ks], c2f[ks], v20, 0, 0, 0);
                    v21 = __builtin_amdgcn_mfma_f32_16x16x32_bf16(c[ks], c2f[ks], v21, 0, 0, 0);
                }
#pragma unroll
                for (int r = 0; r < 4; r++) {
                    float o = p0a[r] * (v20[r] + f2bv) + (1.f - p0a[r]) * (v21[r] + f2bv);
                    if (lm < 15)
                        sO[(mt * 16 + lq * 4 + r) * KP + nn] = f2b(o);
                }
            }
        }
        __syncthreads();

        // ========== phase OUT: out gemm (sO->global) ∥ df gather(i+1)->sA ====
        if (hasnext) {
            float4 g0, g1, g2, g3 = {0.f,0.f,0.f,0.f};
            int a0, a1, a2, a3 = -1;
            {
                int i = tid, p = i / 30, f = i % 30;
                g0 = *(const float4*)(dyn_f + (size_t)s_vi[nxt][p] * DD + f * 4);
                a0 = p * KP + f * 4;
                i += NTHR; p = i / 30; f = i % 30;
                g1 = *(const float4*)(dyn_f + (size_t)s_vi[nxt][p] * DD + f * 4);
                a1 = p * KP + f * 4;
                i += NTHR; p = i / 30; f = i % 30;
                g2 = *(const float4*)(dyn_f + (size_t)s_vi[nxt][p] * DD + f * 4);
                a2 = p * KP + f * 4;
                i += NTHR;
                if (i < MT * 30) {
                    p = i / 30; f = i % 30;
                    g3 = *(const float4*)(dyn_f + (size_t)s_vi[nxt][p] * DD + f * 4);
                    a3 = p * KP + f * 4;
                }
            }
            gemm_out(sO, wt + 7 * 16384, sd_b + 360, out, &s_valid[cur][0],
                     pbase, Mpts, lm, lq, n0t);
            *(uint2*)(sA + a0) = pack4(g0);
            *(uint2*)(sA + a1) = pack4(g1);
            *(uint2*)(sA + a2) = pack4(g2);
            if (a3 >= 0) *(uint2*)(sA + a3) = pack4(g3);
        } else {
            gemm_out(sO, wt + 7 * 16384, sd_b + 360, out, &s_valid[cur][0],
                     pbase, Mpts, lm, lq, n0t);
        }
        __syncthreads();
        cur = nxt;
    }
}

extern "C" void kernel_launch(void* const* d_in, const int* in_sizes, int n_in,
                              void* d_out, int out_size, void* d_ws, size_t ws_size,
                              hipStream_t stream) {
    const float* pts   = (const float*)d_in[0];
    const int*   times = (const int*)d_in[1];
    const int*   vox   = (const int*)d_in[2];
    const float* statf = (const float*)d_in[3];
    const float* dynf  = (const float*)d_in[4];
    const float* temb  = (const float*)d_in[5];
    const float* td_w  = (const float*)d_in[6];
    const float* td_b  = (const float*)d_in[7];
    const float* sd_w  = (const float*)d_in[8];
    const float* sd_b  = (const float*)d_in[9];

    unsigned short* wt  = (unsigned short*)d_ws;          // 8*128*128 bf16 = 256 KB
    unsigned short* k1t = wt + 8 * 128 * 128;             // 201*128 bf16
    unsigned short* v1t = k1t + 201 * 128;                // 201*128 bf16

    prep_weights<<<512, 256, 0, stream>>>(td_w, sd_w, wt);
    prep_te<<<201, 128, 0, stream>>>(temb, td_w, td_b, k1t, v1t);

    int Mpts = in_sizes[0] / 3;
    int ntiles = (Mpts + MT - 1) / MT;
    int blocks = (ntiles < MAXGRID) ? ntiles : MAXGRID;
    voxel_mfma_kernel<<<blocks, NTHR, 0, stream>>>(
        pts, times, vox, statf, dynf, td_b, sd_b, wt, k1t, v1t,
        (float*)d_out, Mpts);
}

// Round 3
// 624.492 us; speedup vs baseline: 1.1250x; 1.1250x over previous
//
#include <hip/hip_runtime.h>
#include <math.h>

#define DD   120
#define KPAD 128
#define KP   136          // LDS row stride in bf16 elems (272 B: 2-way bank alias = free)
#define MT   32           // points per block
#define MTB  2            // MT/16 row-blocks
#define NTHR 256          // 4 waves; wave w owns heads 2w,2w+1
#define HASH_MASK 1048575LL
#define MODT 201

typedef short  short8  __attribute__((ext_vector_type(8)));
typedef float  floatx4 __attribute__((ext_vector_type(4)));

__device__ __forceinline__ unsigned short f2b(float f) {
    __bf16 h = (__bf16)f;                       // RNE hardware cvt
    return __builtin_bit_cast(unsigned short, h);
}
__device__ __forceinline__ float b2f(unsigned short u) {
    unsigned int x = ((unsigned int)u) << 16;   // exact widening
    return __builtin_bit_cast(float, x);
}
// 16-lane sum via DPP row_ror (pure VALU — no DS-pipe latency chain)
template<int CTRL>
__device__ __forceinline__ float dpp_add(float v) {
    int y = __builtin_amdgcn_update_dpp(0, __builtin_bit_cast(int, v),
                                        CTRL, 0xF, 0xF, false);
    return v + __builtin_bit_cast(float, y);
}
__device__ __forceinline__ float rsum16(float v) {
    v = dpp_add<0x128>(v);   // row_ror:8
    v = dpp_add<0x124>(v);   // row_ror:4
    v = dpp_add<0x122>(v);   // row_ror:2
    v = dpp_add<0x121>(v);   // row_ror:1
    return v;
}
__device__ __forceinline__ uint2 pack4(float4 v) {
    unsigned int lo = (unsigned int)f2b(v.x) | ((unsigned int)f2b(v.y) << 16);
    unsigned int hi = (unsigned int)f2b(v.z) | ((unsigned int)f2b(v.w) << 16);
    return make_uint2(lo, hi);
}

// ---------------------------------------------------------------------------
// Pre-pass 1: weights fp32 [K=120][N=120] -> bf16 W^T padded [N=128][K=128].
// ---------------------------------------------------------------------------
__global__ __launch_bounds__(256)
void prep_weights(const float* __restrict__ td_w, const float* __restrict__ sd_w,
                  unsigned short* __restrict__ wt)
{
    int idx = blockIdx.x * 256 + threadIdx.x;   // 8*128*128 = 131072 total
    int mat = idx >> 14;
    int k   = (idx >> 7) & 127;
    int n   = idx & 127;
    const float* src = (mat < 4) ? (td_w + mat * DD * DD) : (sd_w + (mat - 4) * DD * DD);
    float v = (n < DD && k < DD) ? src[k * DD + n] : 0.f;
    wt[(mat << 14) + (n << 7) + k] = f2b(v);
}

// ---------------------------------------------------------------------------
// Pre-pass 2: k1t[t] = te[t]@W1+b1, v1t[t] = te[t]@W2+b2 for 201 time rows.
// ---------------------------------------------------------------------------
__global__ __launch_bounds__(128)
void prep_te(const float* __restrict__ temb, const float* __restrict__ td_w,
             const float* __restrict__ td_b,
             unsigned short* __restrict__ k1t, unsigned short* __restrict__ v1t)
{
    int t = blockIdx.x;      // 0..200
    int n = threadIdx.x;     // 0..127
    float a1 = 0.f, a2 = 0.f;
    if (n < DD) {
        a1 = td_b[DD + n];
        a2 = td_b[2 * DD + n];
        const float* te = temb + t * DD;
        const float* w1 = td_w + 1 * DD * DD;
        const float* w2 = td_w + 2 * DD * DD;
        for (int k = 0; k < DD; k++) {
            float x = te[k];
            a1 = fmaf(x, w1[k * DD + n], a1);
            a2 = fmaf(x, w2[k * DD + n], a2);
        }
    }
    k1t[t * KPAD + n] = f2b(a1);
    v1t[t * KPAD + n] = f2b(a2);
}

// ---------------------------------------------------------------------------
// GEMM pass over one 16-col tile: OUT[32 x 16cols] = IN[32 x 128] @ W + bias.
// ---------------------------------------------------------------------------
__device__ __forceinline__ void gemm_tile(const unsigned short* IN,
                                          const unsigned short* __restrict__ WT,
                                          const float* __restrict__ bias,
                                          unsigned short* OUT,
                                          int lm, int lq, int n0)
{
    const int n = n0 + lm;
    short8 bfr[4];
#pragma unroll
    for (int ks = 0; ks < 4; ks++)
        bfr[ks] = *(const short8*)(WT + n * KPAD + ks * 32 + lq * 8);
    float bv = (n < DD) ? bias[n] : 0.f;
#pragma unroll
    for (int mt = 0; mt < MTB; mt++) {
        floatx4 acc = {0.f, 0.f, 0.f, 0.f};
#pragma unroll
        for (int ks = 0; ks < 4; ks++) {
            short8 a = *(const short8*)(IN + (mt * 16 + lm) * KP + ks * 32 + lq * 8);
            acc = __builtin_amdgcn_mfma_f32_16x16x32_bf16(a, bfr[ks], acc, 0, 0, 0);
        }
#pragma unroll
        for (int r = 0; r < 4; r++)
            OUT[(mt * 16 + lq * 4 + r) * KP + n] = f2b(acc[r] + bv);
    }
}

// Final pass over one 16-col tile: fp32 store to global, masked by valid.
__device__ __forceinline__ void gemm_out(const unsigned short* IN,
                                         const unsigned short* __restrict__ WT,
                                         const float* __restrict__ bias,
                                         float* __restrict__ out,
                                         const int* s_valid, int pbase, int Mpts,
                                         int lm, int lq, int n0)
{
    const int n = n0 + lm;
    short8 bfr[4];
#pragma unroll
    for (int ks = 0; ks < 4; ks++)
        bfr[ks] = *(const short8*)(WT + n * KPAD + ks * 32 + lq * 8);
    float bv = (n < DD) ? bias[n] : 0.f;
#pragma unroll
    for (int mt = 0; mt < MTB; mt++) {
        floatx4 acc = {0.f, 0.f, 0.f, 0.f};
#pragma unroll
        for (int ks = 0; ks < 4; ks++) {
            short8 a = *(const short8*)(IN + (mt * 16 + lm) * KP + ks * 32 + lq * 8);
            acc = __builtin_amdgcn_mfma_f32_16x16x32_bf16(a, bfr[ks], acc, 0, 0, 0);
        }
        if (n < DD) {
#pragma unroll
            for (int r = 0; r < 4; r++) {
                int row = mt * 16 + lq * 4 + r;
                int gp = pbase + row;
                if (gp < Mpts)
                    out[(size_t)gp * DD + n] = s_valid[row] ? (acc[r] + bv) : 0.f;
            }
        }
    }
}

__global__ __launch_bounds__(NTHR, 6)
void voxel_mfma_kernel(const float* __restrict__ pts,
                       const int* __restrict__ times,
                       const int* __restrict__ vox_buf,
                       const float* __restrict__ stat_f,
                       const float* __restrict__ dyn_f,
                       const float* __restrict__ td_b,
                       const float* __restrict__ sd_b,
                       const unsigned short* __restrict__ wt,
                       const unsigned short* __restrict__ k1t,
                       const unsigned short* __restrict__ v1t,
                       float* __restrict__ out,
                       int Mpts)
{
    __shared__ __align__(16) unsigned short sA[MT * KP];
    __shared__ __align__(16) unsigned short sC[MT * KP];
    __shared__ __align__(16) unsigned short sO[MT * KP];
    __shared__ __align__(16) int s_vi[MT];
    __shared__ __align__(16) int s_valid[MT];
    __shared__ __align__(16) int s_ti[MT];

    const int tid  = threadIdx.x;
    const int lane = tid & 63;
    const int lm   = lane & 15;
    const int lq   = lane >> 4;
    const int wv   = tid >> 6;          // wave id 0..3; owns heads 2wv, 2wv+1
    const int pbase = blockIdx.x * MT;
    const float kscale = 0.37250226f;   // log2(e)/sqrt(15)
    const float msk = (lm < 15) ? 1.f : 0.f;

    // ---- phase 0: per-point meta + zero K-pads of sA and sO ----------------
    if (tid < MT) {
        int p = pbase + tid;
        int vi = 0, valid = 0, ti = 0;
        if (p < Mpts) {
            float x = pts[3 * p + 0];
            float y = pts[3 * p + 1];
            float z = pts[3 * p + 2];
            long long gx = (long long)floorf(x / 0.1f);
            long long gy = (long long)floorf(y / 0.1f);
            long long gz = (long long)floorf(z / 0.1f);
            long long hh = (gx * 73856093LL + gy * 19349669LL + gz * 83492791LL) & HASH_MASK;
            int v = vox_buf[(int)hh];
            valid = (v >= 0) ? 1 : 0;
            vi = (v >= 0) ? v : 0;
            ti = times[p] % MODT;
        }
        s_vi[tid] = vi; s_valid[tid] = valid; s_ti[tid] = ti;
    }
    if (tid < 64) {                        // pad cols 120..127 (16 B) of sA, sO
        int b = tid >> 5, p = tid & 31;
        unsigned short* B = b ? sO : sA;
        *(uint4*)(B + p * KP + 120) = make_uint4(0u, 0u, 0u, 0u);
    }
    __syncthreads();

    // ---- phase 1: gather df -> A (fp32->bf16) ------------------------------
    for (int i = tid; i < MT * 30; i += NTHR) {
        int p = i / 30, f = i % 30;
        float4 v = *(const float4*)(dyn_f + (size_t)s_vi[p] * DD + f * 4);
        *(uint2*)(sA + p * KP + f * 4) = pack4(v);
    }
    __syncthreads();

    // ---- phase 2: fusion 1 in registers, per head --------------------------
#pragma unroll
    for (int hh = 0; hh < 2; hh++) {
        const int nn = (2 * wv + hh) * 15 + lm;   // this lane's col, <=120
        const unsigned short* w0 = wt + 0 * 16384;
        const unsigned short* w1 = wt + 1 * 16384;
        const unsigned short* w2 = wt + 2 * 16384;
        short8 bq[4], bk[4], bvv[4];
#pragma unroll
        for (int ks = 0; ks < 4; ks++) {
            bq[ks]  = *(const short8*)(w0 + nn * KPAD + ks * 32 + lq * 8);
            bk[ks]  = *(const short8*)(w1 + nn * KPAD + ks * 32 + lq * 8);
            bvv[ks] = *(const short8*)(w2 + nn * KPAD + ks * 32 + lq * 8);
        }
        const float f1bq = td_b[nn];
        const float f1bk = td_b[120 + nn];
        const float f1bv = td_b[240 + nn];
#pragma unroll
        for (int mt = 0; mt < MTB; mt++) {
            short8 a[4];
#pragma unroll
            for (int ks = 0; ks < 4; ks++)
                a[ks] = *(const short8*)(sA + (mt * 16 + lm) * KP + ks * 32 + lq * 8);
            int4 tiv = *(const int4*)(&s_ti[mt * 16 + lq * 4]);
            int tt[4] = {tiv.x, tiv.y, tiv.z, tiv.w};
            float k1v[4], v1v[4];
#pragma unroll
            for (int r = 0; r < 4; r++) {
                k1v[r] = b2f(k1t[tt[r] * KPAD + nn]);   // bias folded in
                v1v[r] = b2f(v1t[tt[r] * KPAD + nn]);
            }
            floatx4 q = {0.f,0.f,0.f,0.f}, k0 = {0.f,0.f,0.f,0.f}, v0 = {0.f,0.f,0.f,0.f};
#pragma unroll
            for (int ks = 0; ks < 4; ks++) {
                q  = __builtin_amdgcn_mfma_f32_16x16x32_bf16(a[ks], bq[ks],  q,  0, 0, 0);
                k0 = __builtin_amdgcn_mfma_f32_16x16x32_bf16(a[ks], bk[ks],  k0, 0, 0, 0);
                v0 = __builtin_amdgcn_mfma_f32_16x16x32_bf16(a[ks], bvv[ks], v0, 0, 0, 0);
            }
#pragma unroll
            for (int r = 0; r < 4; r++) {
                float qf = (q[r] + f1bq) * msk;
                float c0 = rsum16(qf * (k0[r] + f1bk));
                float c1 = rsum16(qf * k1v[r]);
                float e  = exp2f((c1 - c0) * kscale);
                float p0 = __builtin_amdgcn_rcpf(1.f + e);   // softmax token0
                float o  = p0 * (v0[r] + f1bv) + (e * p0) * v1v[r];
                if (lm < 15)
                    sO[(mt * 16 + lq * 4 + r) * KP + nn] = f2b(o);
            }
        }
    }
    __syncthreads();

    // ---- phase 3: cond = o1@W3+b3 -> C (2 col-tiles) ∥ sf gather -> A ------
    {
        float4 g0, g1, g2, g3 = {0.f,0.f,0.f,0.f};
        int a0, a1, a2, a3 = -1;
        {
            int i = tid, p = i / 30, f = i % 30;
            g0 = *(const float4*)(stat_f + (size_t)s_vi[p] * DD + f * 4);
            a0 = p * KP + f * 4;
            i += NTHR; p = i / 30; f = i % 30;
            g1 = *(const float4*)(stat_f + (size_t)s_vi[p] * DD + f * 4);
            a1 = p * KP + f * 4;
            i += NTHR; p = i / 30; f = i % 30;
            g2 = *(const float4*)(stat_f + (size_t)s_vi[p] * DD + f * 4);
            a2 = p * KP + f * 4;
            i += NTHR;
            if (i < MT * 30) {
                p = i / 30; f = i % 30;
                g3 = *(const float4*)(stat_f + (size_t)s_vi[p] * DD + f * 4);
                a3 = p * KP + f * 4;
            }
        }
        gemm_tile(sO, wt + 3 * 16384, td_b + 360, sC, lm, lq, wv * 16);
        gemm_tile(sO, wt + 3 * 16384, td_b + 360, sC, lm, lq, 64 + wv * 16);
        *(uint2*)(sA + a0) = pack4(g0);
        *(uint2*)(sA + a1) = pack4(g1);
        *(uint2*)(sA + a2) = pack4(g2);
        if (a3 >= 0) *(uint2*)(sA + a3) = pack4(g3);
    }
    __syncthreads();

    // ---- phase 4: fusion 2 in registers, per head --------------------------
#pragma unroll
    for (int hh = 0; hh < 2; hh++) {
        const int nn = (2 * wv + hh) * 15 + lm;
        const unsigned short* u0 = wt + 4 * 16384;
        const unsigned short* u1 = wt + 5 * 16384;
        const unsigned short* u2 = wt + 6 * 16384;
        short8 c1f[4], c2f[4];
#pragma unroll
        for (int ks = 0; ks < 4; ks++) {
            c1f[ks] = *(const short8*)(u1 + nn * KPAD + ks * 32 + lq * 8);
            c2f[ks] = *(const short8*)(u2 + nn * KPAD + ks * 32 + lq * 8);
        }
        const float f2bq = sd_b[nn];
        const float f2bk = sd_b[120 + nn];
        const float f2bv = sd_b[240 + nn];
#pragma unroll
        for (int mt = 0; mt < MTB; mt++) {
            short8 a[4], c[4];
#pragma unroll
            for (int ks = 0; ks < 4; ks++) {
                a[ks] = *(const short8*)(sA + (mt * 16 + lm) * KP + ks * 32 + lq * 8);
                c[ks] = *(const short8*)(sC + (mt * 16 + lm) * KP + ks * 32 + lq * 8);
            }
            floatx4 q = {0.f,0.f,0.f,0.f}, k20 = {0.f,0.f,0.f,0.f}, k21 = {0.f,0.f,0.f,0.f};
#pragma unroll
            for (int ks = 0; ks < 4; ks++) {
                short8 b0 = *(const short8*)(u0 + nn * KPAD + ks * 32 + lq * 8);
                q   = __builtin_amdgcn_mfma_f32_16x16x32_bf16(a[ks], b0,      q,   0, 0, 0);
                k20 = __builtin_amdgcn_mfma_f32_16x16x32_bf16(a[ks], c1f[ks], k20, 0, 0, 0);
                k21 = __builtin_amdgcn_mfma_f32_16x16x32_bf16(c[ks], c1f[ks], k21, 0, 0, 0);
            }
            float p0a[4], p1a[4];
#pragma unroll
            for (int r = 0; r < 4; r++) {
                float qf = (q[r] + f2bq) * msk;
                float c0 = rsum16(qf * (k20[r] + f2bk));
                float c1 = rsum16(qf * (k21[r] + f2bk));
                float e  = exp2f((c1 - c0) * kscale);
                p0a[r] = __builtin_amdgcn_rcpf(1.f + e);
                p1a[r] = e * p0a[r];
            }
            floatx4 v20 = {0.f,0.f,0.f,0.f}, v21 = {0.f,0.f,0.f,0.f};
#pragma unroll
            for (int ks = 0; ks < 4; ks++) {
                v20 = __builtin_amdgcn_mfma_f32_16x16x32_bf16(a[ks], c2f[ks], v20, 0, 0, 0);
                v21 = __builtin_amdgcn_mfma_f32_16x16x32_bf16(c[ks], c2f[ks], v21, 0, 0, 0);
            }
#pragma unroll
            for (int r = 0; r < 4; r++) {
                float o = p0a[r] * (v20[r] + f2bv) + p1a[r] * (v21[r] + f2bv);
                if (lm < 15)
                    sO[(mt * 16 + lq * 4 + r) * KP + nn] = f2b(o);
            }
        }
    }
    __syncthreads();

    // ---- phase 5: out = o2 @ U3 + b (2 col-tiles), masked ------------------
    gemm_out(sO, wt + 7 * 16384, sd_b + 360, out, s_valid, pbase, Mpts, lm, lq, wv * 16);
    gemm_out(sO, wt + 7 * 16384, sd_b + 360, out, s_valid, pbase, Mpts, lm, lq, 64 + wv * 16);
}

extern "C" void kernel_launch(void* const* d_in, const int* in_sizes, int n_in,
                              void* d_out, int out_size, void* d_ws, size_t ws_size,
                              hipStream_t stream) {
    const float* pts   = (const float*)d_in[0];
    const int*   times = (const int*)d_in[1];
    const int*   vox   = (const int*)d_in[2];
    const float* statf = (const float*)d_in[3];
    const float* dynf  = (const float*)d_in[4];
    const float* temb  = (const float*)d_in[5];
    const float* td_w  = (const float*)d_in[6];
    const float* td_b  = (const float*)d_in[7];
    const float* sd_w  = (const float*)d_in[8];
    const float* sd_b  = (const float*)d_in[9];

    unsigned short* wt  = (unsigned short*)d_ws;          // 8*128*128 bf16 = 256 KB
    unsigned short* k1t = wt + 8 * 128 * 128;             // 201*128 bf16
    unsigned short* v1t = k1t + 201 * 128;                // 201*128 bf16

    prep_weights<<<512, 256, 0, stream>>>(td_w, sd_w, wt);
    prep_te<<<201, 128, 0, stream>>>(temb, td_w, td_b, k1t, v1t);

    int Mpts = in_sizes[0] / 3;
    int blocks = (Mpts + MT - 1) / MT;
    voxel_mfma_kernel<<<blocks, NTHR, 0, stream>>>(
        pts, times, vox, statf, dynf, td_b, sd_b, wt, k1t, v1t,
        (float*)d_out, Mpts);
}

// Round 4
// 465.629 us; speedup vs baseline: 1.5089x; 1.3412x over previous
//
#include <hip/hip_runtime.h>
#include <math.h>

#define DD   120
#define KPAD 128
#define KP   136          // LDS row stride in bf16 elems (272 B: 2-way bank alias = free)
#define MT   64           // points per block
#define NTHR 512          // 8 waves; wave h owns head h (cols 15h..15h+14)
#define HASH_MASK 1048575LL
#define MODT 201

typedef short  short8  __attribute__((ext_vector_type(8)));
typedef float  floatx4 __attribute__((ext_vector_type(4)));

__device__ __forceinline__ unsigned short f2b(float f) {
    __bf16 h = (__bf16)f;                       // RNE hardware cvt
    return __builtin_bit_cast(unsigned short, h);
}
__device__ __forceinline__ float b2f(unsigned short u) {
    unsigned int x = ((unsigned int)u) << 16;   // exact widening
    return __builtin_bit_cast(float, x);
}
// 16-lane sum via DPP row_ror (pure VALU — no DS-pipe latency chain)
template<int CTRL>
__device__ __forceinline__ float dpp_add(float v) {
    int y = __builtin_amdgcn_update_dpp(0, __builtin_bit_cast(int, v),
                                        CTRL, 0xF, 0xF, false);
    return v + __builtin_bit_cast(float, y);
}
__device__ __forceinline__ float rsum16(float v) {
    v = dpp_add<0x128>(v);   // row_ror:8
    v = dpp_add<0x124>(v);   // row_ror:4
    v = dpp_add<0x122>(v);   // row_ror:2
    v = dpp_add<0x121>(v);   // row_ror:1
    return v;
}
__device__ __forceinline__ uint2 pack4(float4 v) {
    unsigned int lo = (unsigned int)f2b(v.x) | ((unsigned int)f2b(v.y) << 16);
    unsigned int hi = (unsigned int)f2b(v.z) | ((unsigned int)f2b(v.w) << 16);
    return make_uint2(lo, hi);
}

// ---------------------------------------------------------------------------
// Pre-pass 1: weights fp32 [K=120][N=120] -> bf16 W^T padded [N=128][K=128].
// ---------------------------------------------------------------------------
__global__ __launch_bounds__(256)
void prep_weights(const float* __restrict__ td_w, const float* __restrict__ sd_w,
                  unsigned short* __restrict__ wt)
{
    int idx = blockIdx.x * 256 + threadIdx.x;   // 8*128*128 = 131072 total
    int mat = idx >> 14;
    int k   = (idx >> 7) & 127;
    int n   = idx & 127;
    const float* src = (mat < 4) ? (td_w + mat * DD * DD) : (sd_w + (mat - 4) * DD * DD);
    float v = (n < DD && k < DD) ? src[k * DD + n] : 0.f;
    wt[(mat << 14) + (n << 7) + k] = f2b(v);
}

// ---------------------------------------------------------------------------
// Pre-pass 2: k1t[t] = te[t]@W1+b1, v1t[t] = te[t]@W2+b2 for 201 time rows.
// ---------------------------------------------------------------------------
__global__ __launch_bounds__(128)
void prep_te(const float* __restrict__ temb, const float* __restrict__ td_w,
             const float* __restrict__ td_b,
             unsigned short* __restrict__ k1t, unsigned short* __restrict__ v1t)
{
    int t = blockIdx.x;      // 0..200
    int n = threadIdx.x;     // 0..127
    float a1 = 0.f, a2 = 0.f;
    if (n < DD) {
        a1 = td_b[DD + n];
        a2 = td_b[2 * DD + n];
        const float* te = temb + t * DD;
        const float* w1 = td_w + 1 * DD * DD;
        const float* w2 = td_w + 2 * DD * DD;
        for (int k = 0; k < DD; k++) {
            float x = te[k];
            a1 = fmaf(x, w1[k * DD + n], a1);
            a2 = fmaf(x, w2[k * DD + n], a2);
        }
    }
    k1t[t * KPAD + n] = f2b(a1);
    v1t[t * KPAD + n] = f2b(a2);
}

// ---------------------------------------------------------------------------
// GEMM pass: OUT[64 x 16cols] = IN[64 x 128] @ W + bias, this wave's N-tile.
// A frag: lane holds IN[m=lane&15][k=quad*8..+8]  (ds_read_b128)
// B frag: lane holds W^T[n=lane&15][k=quad*8..+8] (global 16B load, L2-hot)
// C:      col = lane&15, row = quad*4 + reg       [m89-verified layout]
// ---------------------------------------------------------------------------
__device__ __forceinline__ void gemm_tile(const unsigned short* IN,
                                          const unsigned short* __restrict__ WT,
                                          const float* __restrict__ bias,
                                          unsigned short* OUT,
                                          int lm, int lq, int n0)
{
    const int n = n0 + lm;
    short8 bfr[4];
#pragma unroll
    for (int ks = 0; ks < 4; ks++)
        bfr[ks] = *(const short8*)(WT + n * KPAD + ks * 32 + lq * 8);
    float bv = (n < DD) ? bias[n] : 0.f;
#pragma unroll
    for (int mt = 0; mt < 4; mt++) {
        floatx4 acc = {0.f, 0.f, 0.f, 0.f};
#pragma unroll
        for (int ks = 0; ks < 4; ks++) {
            short8 a = *(const short8*)(IN + (mt * 16 + lm) * KP + ks * 32 + lq * 8);
            acc = __builtin_amdgcn_mfma_f32_16x16x32_bf16(a, bfr[ks], acc, 0, 0, 0);
        }
#pragma unroll
        for (int r = 0; r < 4; r++)
            OUT[(mt * 16 + lq * 4 + r) * KP + n] = f2b(acc[r] + bv);
    }
}

// Final pass: fp32 store straight to global, masked by valid (s_vr sign).
__device__ __forceinline__ void gemm_out(const unsigned short* IN,
                                         const unsigned short* __restrict__ WT,
                                         const float* __restrict__ bias,
                                         float* __restrict__ out,
                                         const int* s_vr, int pbase, int Mpts,
                                         int lm, int lq, int n0)
{
    const int n = n0 + lm;
    short8 bfr[4];
#pragma unroll
    for (int ks = 0; ks < 4; ks++)
        bfr[ks] = *(const short8*)(WT + n * KPAD + ks * 32 + lq * 8);
    float bv = (n < DD) ? bias[n] : 0.f;
#pragma unroll
    for (int mt = 0; mt < 4; mt++) {
        floatx4 acc = {0.f, 0.f, 0.f, 0.f};
#pragma unroll
        for (int ks = 0; ks < 4; ks++) {
            short8 a = *(const short8*)(IN + (mt * 16 + lm) * KP + ks * 32 + lq * 8);
            acc = __builtin_amdgcn_mfma_f32_16x16x32_bf16(a, bfr[ks], acc, 0, 0, 0);
        }
        if (n < DD) {
#pragma unroll
            for (int r = 0; r < 4; r++) {
                int row = mt * 16 + lq * 4 + r;
                int gp = pbase + row;
                if (gp < Mpts)
                    out[(size_t)gp * DD + n] = (s_vr[row] >= 0) ? (acc[r] + bv) : 0.f;
            }
        }
    }
}

__global__ __launch_bounds__(NTHR, 4)
void voxel_mfma_kernel(const float* __restrict__ pts,
                       const int* __restrict__ times,
                       const int* __restrict__ vox_buf,
                       const float* __restrict__ stat_f,
                       const float* __restrict__ dyn_f,
                       const float* __restrict__ td_b,
                       const float* __restrict__ sd_b,
                       const unsigned short* __restrict__ wt,
                       const unsigned short* __restrict__ k1t,
                       const unsigned short* __restrict__ v1t,
                       float* __restrict__ out,
                       int Mpts)
{
    __shared__ __align__(16) unsigned short sA[MT * KP];
    __shared__ __align__(16) unsigned short sC[MT * KP];
    __shared__ __align__(16) unsigned short sO[MT * KP];
    __shared__ __align__(16) int s_vr[MT];   // raw voxel index; <0 => invalid
    __shared__ __align__(16) int s_ti[MT];

    const int tid  = threadIdx.x;
    const int lane = tid & 63;
    const int lm   = lane & 15;
    const int lq   = lane >> 4;
    const int wv   = tid >> 6;          // wave id = head id
    const int n0h  = wv * 15;           // head-aligned col base (reg QKV passes)
    const int n0t  = wv * 16;           // 16-col tiles (cond / out gemm)
    const int nn   = n0h + lm;          // this lane's col in reg passes (<=120)
    const int pbase = blockIdx.x * MT;
    const float kscale = 0.37250226f;   // log2(e)/sqrt(15)
    const float msk = (lm < 15) ? 1.f : 0.f;

    // ---- fused prologue: 8 threads per point do meta chain + df gather -----
    // Removes the meta->gather barrier; the 3-deep dependent chain
    // (pts -> vox_buf -> dyn_f row) issues from all 512 threads in parallel.
    {
        const int p   = tid >> 3;       // local point 0..63
        const int sub = tid & 7;
        const int gp  = pbase + p;
        int vr = -1, ti = 0;
        if (gp < Mpts) {
            float x = pts[3 * gp + 0];
            float y = pts[3 * gp + 1];
            float z = pts[3 * gp + 2];
            long long gx = (long long)floorf(x / 0.1f);
            long long gy = (long long)floorf(y / 0.1f);
            long long gz = (long long)floorf(z / 0.1f);
            long long hh = (gx * 73856093LL + gy * 19349669LL + gz * 83492791LL) & HASH_MASK;
            vr = vox_buf[(int)hh];
            ti = times[gp] % MODT;
        }
        if (sub == 0) { s_vr[p] = vr; s_ti[p] = ti; }
        const int vi = (vr >= 0) ? vr : 0;      // safe row even when invalid/OOB
        const float* drow = dyn_f + (size_t)vi * DD;
#pragma unroll
        for (int j = 0; j < 4; j++) {
            int f = sub + 8 * j;                // consecutive subs -> coalesced
            if (f < 30) {
                float4 v = *(const float4*)(drow + f * 4);
                *(uint2*)(sA + p * KP + f * 4) = pack4(v);
            }
        }
        if (sub == 7) {                         // zero K-pads (cols 120..127)
            *(uint4*)(sA + p * KP + 120) = make_uint4(0u, 0u, 0u, 0u);
            *(uint4*)(sO + p * KP + 120) = make_uint4(0u, 0u, 0u, 0u);
        }
    }
    __syncthreads();

    // ---- phase F1: fusion 1 entirely in registers --------------------------
    // Q,K0,V0 = df@W0/1/2 in MFMA accs (head-aligned cols); K1,V1 scalar-read
    // from L2-hot time tables; scores via DPP reduce; o1 -> sO.
    {
        const unsigned short* w0 = wt + 0 * 16384;
        const unsigned short* w1 = wt + 1 * 16384;
        const unsigned short* w2 = wt + 2 * 16384;
        short8 bq[4], bk[4], bvv[4];
#pragma unroll
        for (int ks = 0; ks < 4; ks++) {
            bq[ks]  = *(const short8*)(w0 + nn * KPAD + ks * 32 + lq * 8);
            bk[ks]  = *(const short8*)(w1 + nn * KPAD + ks * 32 + lq * 8);
            bvv[ks] = *(const short8*)(w2 + nn * KPAD + ks * 32 + lq * 8);
        }
        const float f1bq = td_b[nn];
        const float f1bk = td_b[120 + nn];
        const float f1bv = td_b[240 + nn];
#pragma unroll
        for (int mt = 0; mt < 4; mt++) {
            short8 a[4];
#pragma unroll
            for (int ks = 0; ks < 4; ks++)
                a[ks] = *(const short8*)(sA + (mt * 16 + lm) * KP + ks * 32 + lq * 8);
            int4 tiv = *(const int4*)(&s_ti[mt * 16 + lq * 4]);
            int tt[4] = {tiv.x, tiv.y, tiv.z, tiv.w};
            float k1v[4], v1v[4];
#pragma unroll
            for (int r = 0; r < 4; r++) {
                k1v[r] = b2f(k1t[tt[r] * KPAD + nn]);   // bias folded in
                v1v[r] = b2f(v1t[tt[r] * KPAD + nn]);
            }
            floatx4 q = {0.f,0.f,0.f,0.f}, k0 = {0.f,0.f,0.f,0.f}, v0 = {0.f,0.f,0.f,0.f};
#pragma unroll
            for (int ks = 0; ks < 4; ks++) {
                q  = __builtin_amdgcn_mfma_f32_16x16x32_bf16(a[ks], bq[ks],  q,  0, 0, 0);
                k0 = __builtin_amdgcn_mfma_f32_16x16x32_bf16(a[ks], bk[ks],  k0, 0, 0, 0);
                v0 = __builtin_amdgcn_mfma_f32_16x16x32_bf16(a[ks], bvv[ks], v0, 0, 0, 0);
            }
#pragma unroll
            for (int r = 0; r < 4; r++) {
                float qf = (q[r] + f1bq) * msk;
                float c0 = rsum16(qf * (k0[r] + f1bk));
                float c1 = rsum16(qf * k1v[r]);
                float e  = exp2f((c1 - c0) * kscale);
                float p0 = __builtin_amdgcn_rcpf(1.f + e);   // softmax token0
                float o  = p0 * (v0[r] + f1bv) + (e * p0) * v1v[r];
                if (lm < 15)
                    sO[(mt * 16 + lq * 4 + r) * KP + nn] = f2b(o);
            }
        }
    }
    __syncthreads();

    // ---- phase COND: cond = o1@W3+b3 -> sC, OVERLAPPED with sf gather -> sA
    {
        float4 g0, g1, g2, g3 = {0.f,0.f,0.f,0.f};
        int a0, a1, a2, a3 = -1;
        {
            int i = tid, p = i / 30, f = i % 30;
            int vi0 = s_vr[p] >= 0 ? s_vr[p] : 0;
            g0 = *(const float4*)(stat_f + (size_t)vi0 * DD + f * 4);
            a0 = p * KP + f * 4;
            i += NTHR; p = i / 30; f = i % 30;
            int vi1 = s_vr[p] >= 0 ? s_vr[p] : 0;
            g1 = *(const float4*)(stat_f + (size_t)vi1 * DD + f * 4);
            a1 = p * KP + f * 4;
            i += NTHR; p = i / 30; f = i % 30;
            int vi2 = s_vr[p] >= 0 ? s_vr[p] : 0;
            g2 = *(const float4*)(stat_f + (size_t)vi2 * DD + f * 4);
            a2 = p * KP + f * 4;
            i += NTHR;
            if (i < MT * 30) {
                p = i / 30; f = i % 30;
                int vi3 = s_vr[p] >= 0 ? s_vr[p] : 0;
                g3 = *(const float4*)(stat_f + (size_t)vi3 * DD + f * 4);
                a3 = p * KP + f * 4;
            }
        }
        gemm_tile(sO, wt + 3 * 16384, td_b + 360, sC, lm, lq, n0t);
        *(uint2*)(sA + a0) = pack4(g0);
        *(uint2*)(sA + a1) = pack4(g1);
        *(uint2*)(sA + a2) = pack4(g2);
        if (a3 >= 0) *(uint2*)(sA + a3) = pack4(g3);
    }
    __syncthreads();

    // ---- phase F2: fusion 2 entirely in registers --------------------------
    {
        const unsigned short* u0 = wt + 4 * 16384;
        const unsigned short* u1 = wt + 5 * 16384;
        const unsigned short* u2 = wt + 6 * 16384;
        short8 c1f[4], c2f[4];
#pragma unroll
        for (int ks = 0; ks < 4; ks++) {
            c1f[ks] = *(const short8*)(u1 + nn * KPAD + ks * 32 + lq * 8);
            c2f[ks] = *(const short8*)(u2 + nn * KPAD + ks * 32 + lq * 8);
        }
        const float f2bq = sd_b[nn];
        const float f2bk = sd_b[120 + nn];
        const float f2bv = sd_b[240 + nn];
#pragma unroll
        for (int mt = 0; mt < 4; mt++) {
            short8 a[4], c[4];
#pragma unroll
            for (int ks = 0; ks < 4; ks++) {
                a[ks] = *(const short8*)(sA + (mt * 16 + lm) * KP + ks * 32 + lq * 8);
                c[ks] = *(const short8*)(sC + (mt * 16 + lm) * KP + ks * 32 + lq * 8);
            }
            floatx4 q = {0.f,0.f,0.f,0.f}, k20 = {0.f,0.f,0.f,0.f}, k21 = {0.f,0.f,0.f,0.f};
#pragma unroll
            for (int ks = 0; ks < 4; ks++) {
                short8 b0 = *(const short8*)(u0 + nn * KPAD + ks * 32 + lq * 8);
                q   = __builtin_amdgcn_mfma_f32_16x16x32_bf16(a[ks], b0,      q,   0, 0, 0);
                k20 = __builtin_amdgcn_mfma_f32_16x16x32_bf16(a[ks], c1f[ks], k20, 0, 0, 0);
                k21 = __builtin_amdgcn_mfma_f32_16x16x32_bf16(c[ks], c1f[ks], k21, 0, 0, 0);
            }
            float p0a[4], p1a[4];
#pragma unroll
            for (int r = 0; r < 4; r++) {
                float qf = (q[r] + f2bq) * msk;
                float c0 = rsum16(qf * (k20[r] + f2bk));
                float c1 = rsum16(qf * (k21[r] + f2bk));
                float e  = exp2f((c1 - c0) * kscale);
                p0a[r] = __builtin_amdgcn_rcpf(1.f + e);
                p1a[r] = e * p0a[r];
            }
            floatx4 v20 = {0.f,0.f,0.f,0.f}, v21 = {0.f,0.f,0.f,0.f};
#pragma unroll
            for (int ks = 0; ks < 4; ks++) {
                v20 = __builtin_amdgcn_mfma_f32_16x16x32_bf16(a[ks], c2f[ks], v20, 0, 0, 0);
                v21 = __builtin_amdgcn_mfma_f32_16x16x32_bf16(c[ks], c2f[ks], v21, 0, 0, 0);
            }
#pragma unroll
            for (int r = 0; r < 4; r++) {
                float o = p0a[r] * (v20[r] + f2bv) + p1a[r] * (v21[r] + f2bv);
                if (lm < 15)
                    sO[(mt * 16 + lq * 4 + r) * KP + nn] = f2b(o);
            }
        }
    }
    __syncthreads();

    // ---- phase OUT: out = o2 @ U3 + b, masked ------------------------------
    gemm_out(sO, wt + 7 * 16384, sd_b + 360, out, s_vr, pbase, Mpts, lm, lq, n0t);
}

extern "C" void kernel_launch(void* const* d_in, const int* in_sizes, int n_in,
                              void* d_out, int out_size, void* d_ws, size_t ws_size,
                              hipStream_t stream) {
    const float* pts   = (const float*)d_in[0];
    const int*   times = (const int*)d_in[1];
    const int*   vox   = (const int*)d_in[2];
    const float* statf = (const float*)d_in[3];
    const float* dynf  = (const float*)d_in[4];
    const float* temb  = (const float*)d_in[5];
    const float* td_w  = (const float*)d_in[6];
    const float* td_b  = (const float*)d_in[7];
    const float* sd_w  = (const float*)d_in[8];
    const float* sd_b  = (const float*)d_in[9];

    unsigned short* wt  = (unsigned short*)d_ws;          // 8*128*128 bf16 = 256 KB
    unsigned short* k1t = wt + 8 * 128 * 128;             // 201*128 bf16
    unsigned short* v1t = k1t + 201 * 128;                // 201*128 bf16

    prep_weights<<<512, 256, 0, stream>>>(td_w, sd_w, wt);
    prep_te<<<201, 128, 0, stream>>>(temb, td_w, td_b, k1t, v1t);

    int Mpts = in_sizes[0] / 3;
    int blocks = (Mpts + MT - 1) / MT;
    voxel_mfma_kernel<<<blocks, NTHR, 0, stream>>>(
        pts, times, vox, statf, dynf, td_b, sd_b, wt, k1t, v1t,
        (float*)d_out, Mpts);
}